// Round 2
// baseline (433.177 us; speedup 1.0000x reference)
//
#include <hip/hip_runtime.h>
#include <hip/hip_bf16.h>

#define VOCAB   50000
#define BATCH   256
#define SEQ     512
#define NM1     1024
#define NM2     512
#define NEMB    256
#define KB1     782            /* ceil(50000/64) */
#define KPAD    (KB1*64)       /* 50048 */
#define SPLITK  32

typedef __attribute__((ext_vector_type(8))) short short8;
typedef __attribute__((ext_vector_type(4))) float f32x4;

#define BOW_BYTES   ((size_t)BATCH * KPAD * 4)            /* 51,249,152 */
#define PART_BYTES  ((size_t)SPLITK * BATCH * NM1 * 4)    /* 33,554,432 */

__device__ __forceinline__ short f2b(float x) {
    __hip_bfloat16 b = __float2bfloat16(x);
    return __builtin_bit_cast(short, b);
}

// ---------------------------------------------------------------- histogram
__global__ void BOW_hist(const int* __restrict__ idx, float* __restrict__ bow) {
    int i = blockIdx.x;
    int t = threadIdx.x;
    #pragma unroll
    for (int j = t; j < SEQ; j += 256) {
        int v = idx[i * SEQ + j];
        atomicAdd(&bow[(size_t)i * KPAD + v], 1.0f);
    }
}

// ---------------------------------------------------------------- GEMM1
// C_partial[s][256][1024] += bow[256][K-chunk] * W1[1024][K-chunk]^T  (bf16 MFMA)
// grid = SPLITK(32) * NT(8) = 256 blocks, 512 threads (8 waves, 4m x 2n)
__global__ __launch_bounds__(512) void BOW_gemm1(
        const float* __restrict__ bow,    // [256][KPAD], zero-padded
        const float* __restrict__ W1,     // [1024][50000]
        float* __restrict__ partials)     // [SPLITK][256][1024]
{
    __shared__ __align__(16) __hip_bfloat16 As[256 * 64];  // swizzled
    __shared__ __align__(16) __hip_bfloat16 Bs[128 * 64];  // swizzled

    const int tid = threadIdx.x;
    const int bid = blockIdx.x;
    const int s   = bid >> 3;         // split 0..31
    const int nt  = bid & 7;          // n-tile 0..7
    const int n0  = nt * 128;

    // 782 kblocks over 32 splits: 14 splits of 25, 18 of 24
    const int kb_start = s * 24 + (s < 14 ? s : 14);
    const int kb_count = 24 + (s < 14 ? 1 : 0);

    const int lane = tid & 63;
    const int w    = tid >> 6;        // 0..7
    const int wm   = w >> 1;          // 0..3 (rows of 64)
    const int wn   = w & 1;           // 0..1 (cols of 64)

    f32x4 acc[4][4];
    #pragma unroll
    for (int m = 0; m < 4; m++)
        #pragma unroll
        for (int n = 0; n < 4; n++) acc[m][n] = (f32x4){0.f, 0.f, 0.f, 0.f};

    for (int kb = kb_start; kb < kb_start + kb_count; ++kb) {
        const int kg0 = kb * 64;

        // ---- stage A: 256x64 fp32 -> bf16, 4 chunks of 8 elems per thread
        #pragma unroll
        for (int r = 0; r < 4; r++) {
            int c   = tid + 512 * r;
            int row = c >> 3;
            int k8  = c & 7;
            const float* src = bow + (size_t)row * KPAD + kg0 + k8 * 8;
            float4 v0 = *reinterpret_cast<const float4*>(src);
            float4 v1 = *reinterpret_cast<const float4*>(src + 4);
            short8 p;
            p[0] = f2b(v0.x); p[1] = f2b(v0.y); p[2] = f2b(v0.z); p[3] = f2b(v0.w);
            p[4] = f2b(v1.x); p[5] = f2b(v1.y); p[6] = f2b(v1.z); p[7] = f2b(v1.w);
            int dst = row * 64 + ((k8 * 8) ^ ((row & 7) << 3));
            *reinterpret_cast<short8*>(&As[dst]) = p;
        }
        // ---- stage B: 128x64 fp32 -> bf16, 2 chunks per thread (guard K tail)
        #pragma unroll
        for (int r = 0; r < 2; r++) {
            int c   = tid + 512 * r;
            int row = c >> 3;
            int k8  = c & 7;
            int kg  = kg0 + k8 * 8;
            float4 v0 = {0.f,0.f,0.f,0.f}, v1 = {0.f,0.f,0.f,0.f};
            if (kg < VOCAB) {   // VOCAB % 8 == 0 -> chunk fully valid or fully out
                const float* src = W1 + (size_t)(n0 + row) * VOCAB + kg;
                v0 = *reinterpret_cast<const float4*>(src);
                v1 = *reinterpret_cast<const float4*>(src + 4);
            }
            short8 p;
            p[0] = f2b(v0.x); p[1] = f2b(v0.y); p[2] = f2b(v0.z); p[3] = f2b(v0.w);
            p[4] = f2b(v1.x); p[5] = f2b(v1.y); p[6] = f2b(v1.z); p[7] = f2b(v1.w);
            int dst = row * 64 + ((k8 * 8) ^ ((row & 7) << 3));
            *reinterpret_cast<short8*>(&Bs[dst]) = p;
        }
        __syncthreads();

        // ---- MFMA: 2 kk-halves of 32, 4x4 fragments of 16x16 per wave
        #pragma unroll
        for (int kk = 0; kk < 2; kk++) {
            short8 a[4], b[4];
            const int kf = kk * 32 + ((lane >> 4) << 3);
            #pragma unroll
            for (int m = 0; m < 4; m++) {
                int row = wm * 64 + m * 16 + (lane & 15);
                int e   = row * 64 + (kf ^ ((row & 7) << 3));
                a[m] = *reinterpret_cast<const short8*>(&As[e]);
            }
            #pragma unroll
            for (int n = 0; n < 4; n++) {
                int row = wn * 64 + n * 16 + (lane & 15);
                int e   = row * 64 + (kf ^ ((row & 7) << 3));
                b[n] = *reinterpret_cast<const short8*>(&Bs[e]);
            }
            #pragma unroll
            for (int m = 0; m < 4; m++)
                #pragma unroll
                for (int n = 0; n < 4; n++)
                    acc[m][n] = __builtin_amdgcn_mfma_f32_16x16x32_bf16(
                                    a[m], b[n], acc[m][n], 0, 0, 0);
        }
        __syncthreads();
    }

    // ---- epilogue: write fp32 partial tile
    float* dst = partials + (size_t)s * (BATCH * NM1);
    #pragma unroll
    for (int m = 0; m < 4; m++) {
        #pragma unroll
        for (int n = 0; n < 4; n++) {
            int col = n0 + wn * 64 + n * 16 + (lane & 15);
            #pragma unroll
            for (int j = 0; j < 4; j++) {
                int rowi = wm * 64 + m * 16 + ((lane >> 4) * 4 + j);
                dst[(size_t)rowi * NM1 + col] = acc[m][n][j];
            }
        }
    }
}

// ---------------------------------------------------------------- reduce + bias + relu
__global__ void BOW_reduce1(const float* __restrict__ partials,
                            const float* __restrict__ b1,
                            float* __restrict__ h1) {
    int o = blockIdx.x * 256 + threadIdx.x;   // 262144 outputs
    int m = o & (NM1 - 1);
    float s = b1[m];
    #pragma unroll
    for (int sp = 0; sp < SPLITK; sp++) s += partials[(size_t)sp * (BATCH * NM1) + o];
    h1[o] = fmaxf(s, 0.f);
}

// ---------------------------------------------------------------- small fp32 GEMM
// out[256][N] = relu(A[256][K] @ Bw[N][K]^T + bias), tile 32x32, BK=32
__global__ void BOW_gemm_f32(const float* __restrict__ A,
                             const float* __restrict__ Bw,
                             const float* __restrict__ bias,
                             float* __restrict__ out,
                             int N, int K) {
    __shared__ float As[32][33];
    __shared__ float Bs[32][33];
    int tid = threadIdx.x;
    int i0 = blockIdx.y * 32, n0 = blockIdx.x * 32;
    int r = tid >> 5, c = tid & 31;
    int ty = tid >> 4, tx = tid & 15;
    float a2[2][2] = {{0.f, 0.f}, {0.f, 0.f}};

    for (int k0 = 0; k0 < K; k0 += 32) {
        #pragma unroll
        for (int rr = 0; rr < 4; rr++) {
            As[r + rr * 8][c] = A[(size_t)(i0 + r + rr * 8) * K + k0 + c];
            Bs[r + rr * 8][c] = Bw[(size_t)(n0 + r + rr * 8) * K + k0 + c];
        }
        __syncthreads();
        #pragma unroll
        for (int k = 0; k < 32; k++) {
            float av0 = As[ty * 2][k],     av1 = As[ty * 2 + 1][k];
            float bv0 = Bs[tx * 2][k],     bv1 = Bs[tx * 2 + 1][k];
            a2[0][0] += av0 * bv0; a2[0][1] += av0 * bv1;
            a2[1][0] += av1 * bv0; a2[1][1] += av1 * bv1;
        }
        __syncthreads();
    }
    #pragma unroll
    for (int ii = 0; ii < 2; ii++)
        #pragma unroll
        for (int nn = 0; nn < 2; nn++) {
            int i = i0 + ty * 2 + ii, n = n0 + tx * 2 + nn;
            out[(size_t)i * N + n] = fmaxf(a2[ii][nn] + bias[n], 0.f);
        }
}

// ---------------------------------------------------------------- launcher
extern "C" void kernel_launch(void* const* d_in, const int* in_sizes, int n_in,
                              void* d_out, int out_size, void* d_ws, size_t ws_size,
                              hipStream_t stream) {
    const int*   idx = (const int*)d_in[0];
    const float* W1  = (const float*)d_in[1];
    const float* b1  = (const float*)d_in[2];
    const float* W2  = (const float*)d_in[3];
    const float* b2  = (const float*)d_in[4];
    const float* W3  = (const float*)d_in[5];
    const float* b3  = (const float*)d_in[6];
    float* out = (float*)d_out;

    char* ws = (char*)d_ws;
    float* bow      = (float*)ws;
    float* partials = (float*)(ws + BOW_BYTES);
    float* h1       = (float*)(ws + BOW_BYTES + PART_BYTES);
    float* h2       = h1 + BATCH * NM1;

    hipMemsetAsync(bow, 0, BOW_BYTES, stream);
    BOW_hist<<<BATCH, 256, 0, stream>>>(idx, bow);
    BOW_gemm1<<<SPLITK * 8, 512, 0, stream>>>(bow, W1, partials);
    BOW_reduce1<<<(BATCH * NM1) / 256, 256, 0, stream>>>(partials, b1, h1);
    BOW_gemm_f32<<<dim3(NM2 / 32, BATCH / 32), 256, 0, stream>>>(h1, W2, b2, h2, NM2, NM1);
    BOW_gemm_f32<<<dim3(NEMB / 32, BATCH / 32), 256, 0, stream>>>(h2, W3, b3, out, NEMB, NM2);
}

// Round 3
// 405.541 us; speedup vs baseline: 1.0681x; 1.0681x over previous
//
#include <hip/hip_runtime.h>
#include <hip/hip_bf16.h>

#define VOCAB   50000
#define BATCH   256
#define SEQ     512
#define NM1     1024
#define NM2     512
#define NEMB    256
#define KB1     782            /* ceil(50000/64) */
#define KPAD    (KB1*64)       /* 50048 */
#define SPLITK  32
#define NT      16             /* n-tiles of 64 */
#define HHALF   (KPAD/2)       /* 25024 vocab entries per hist block */

typedef __attribute__((ext_vector_type(8))) short short8;
typedef __attribute__((ext_vector_type(4))) float f32x4;

#define BOW_BYTES   ((size_t)BATCH * KPAD * 2)            /* 25,624,576 (bf16) */
#define PART_BYTES  ((size_t)SPLITK * BATCH * NM1 * 4)    /* 33,554,432 */

__device__ __forceinline__ short f2b(float x) {
    __hip_bfloat16 b = __float2bfloat16(x);
    return __builtin_bit_cast(short, b);
}
__device__ __forceinline__ unsigned short f2bu(float x) {
    __hip_bfloat16 b = __float2bfloat16(x);
    return __builtin_bit_cast(unsigned short, b);
}

// ---------------------------------------------------------------- histogram -> bf16 bow
// 2 blocks per batch row; each owns half the vocab range in an LDS u16 histogram
// (packed as u32 pairs), then writes its half-row as bf16. Counts <= 512 -> bf16 exact
// for the random-data regime (max dup count ~6; exact up to 256 and at 512).
__global__ __launch_bounds__(256) void BOW_hist2(const int* __restrict__ idx,
                                                 __hip_bfloat16* __restrict__ bow) {
    __shared__ unsigned int h[HHALF / 2];    // 12512 words = 50,048 B
    const int b    = blockIdx.x;
    const int row  = b >> 1;
    const int lo   = (b & 1) * HHALF;
    const int t    = threadIdx.x;

    for (int j = t; j < HHALF / 2; j += 256) h[j] = 0u;
    __syncthreads();

    #pragma unroll
    for (int u = 0; u < 2; u++) {
        int v = idx[row * SEQ + u * 256 + t];
        int d = v - lo;
        if ((unsigned)d < (unsigned)HHALF)
            atomicAdd(&h[d >> 1], (d & 1) ? 0x10000u : 1u);
    }
    __syncthreads();

    unsigned int* dst = (unsigned int*)(bow + (size_t)row * KPAD + lo);
    for (int j = t; j < HHALF / 2; j += 256) {
        unsigned int w  = h[j];
        unsigned int l16 = f2bu((float)(w & 0xFFFFu));
        unsigned int h16 = f2bu((float)(w >> 16));
        dst[j] = l16 | (h16 << 16);
    }
}

// ---------------------------------------------------------------- GEMM1
// partials[s][256][1024] += bow[256][Kchunk] * W1[64-chunk][Kchunk]^T  (bf16 MFMA)
// grid = SPLITK(32) * NT(16) = 512 blocks (2/CU), 512 threads (8 waves, 4m x 2n)
// A (bf16 bow) staged via global_load_lds w16, pre-swizzled source; B reg-converted.
__global__ __launch_bounds__(512) void BOW_gemm1(
        const __hip_bfloat16* __restrict__ bow,   // [256][KPAD], zero tail
        const float* __restrict__ W1,             // [1024][50000]
        float* __restrict__ partials)             // [SPLITK][256][1024]
{
    __shared__ __align__(16) __hip_bfloat16 As[256 * 64];  // 32 KB, swizzled
    __shared__ __align__(16) __hip_bfloat16 Bs[64 * 64];   //  8 KB, swizzled

    const int tid = threadIdx.x;
    const int bid = blockIdx.x;
    const int s   = bid >> 4;          // split 0..31
    const int nt  = bid & 15;          // n-tile 0..15
    const int n0  = nt * 64;

    // 782 kblocks over 32 splits: 14 splits of 25, 18 of 24
    const int kb_start = s * 24 + (s < 14 ? s : 14);
    const int kb_count = 24 + (s < 14 ? 1 : 0);

    const int lane = tid & 63;
    const int w    = tid >> 6;         // 0..7
    const int wm   = w >> 1;           // 0..3 (row group of 64)
    const int wn   = w & 1;            // 0..1 (col group of 32)

    f32x4 acc[4][2];
    #pragma unroll
    for (int m = 0; m < 4; m++)
        #pragma unroll
        for (int n = 0; n < 2; n++) acc[m][n] = (f32x4){0.f, 0.f, 0.f, 0.f};

    // B staging indices (fixed per thread): 64 rows x 8 chunks of 8 f32
    const int brow = tid >> 3;
    const int bk8  = tid & 7;
    const int bdst = brow * 64 + ((bk8 * 8) ^ ((brow & 7) << 3));
    const float* wsrc = W1 + (size_t)(n0 + brow) * VOCAB + bk8 * 8;

    for (int kb = kb_start; kb < kb_start + kb_count; ++kb) {
        const int kg0 = kb * 64;

        // ---- stage A: 256x64 bf16 via global_load_lds (16B/lane, linear LDS dest,
        //      pre-swizzled global source)
        #pragma unroll
        for (int i = 0; i < 4; i++) {
            int c   = i * 512 + tid;
            int row = c >> 3;
            int k8  = c & 7;
            const __hip_bfloat16* src =
                bow + (size_t)row * KPAD + kg0 + ((k8 * 8) ^ ((row & 7) << 3));
            __builtin_amdgcn_global_load_lds(
                (const __attribute__((address_space(1))) void*)src,
                (__attribute__((address_space(3))) void*)&As[c * 8], 16, 0, 0);
        }

        // ---- stage B: 64x64 fp32 -> bf16 (8 f32/thread), swizzled store
        {
            int kg = kg0 + bk8 * 8;
            float4 v0 = {0.f,0.f,0.f,0.f}, v1 = {0.f,0.f,0.f,0.f};
            if (kg < VOCAB) {   // chunks are fully valid or fully out (50000-49984=16)
                const float* src = wsrc + kg0;
                v0 = *reinterpret_cast<const float4*>(src);
                v1 = *reinterpret_cast<const float4*>(src + 4);
            }
            short8 p;
            p[0] = f2b(v0.x); p[1] = f2b(v0.y); p[2] = f2b(v0.z); p[3] = f2b(v0.w);
            p[4] = f2b(v1.x); p[5] = f2b(v1.y); p[6] = f2b(v1.z); p[7] = f2b(v1.w);
            *reinterpret_cast<short8*>(&Bs[bdst]) = p;
        }
        __syncthreads();

        // ---- MFMA: 2 kk-halves of 32, 4m x 2n fragments of 16x16 per wave
        #pragma unroll
        for (int kk = 0; kk < 2; kk++) {
            short8 a[4], b[2];
            const int kf = kk * 32 + ((lane >> 4) << 3);
            #pragma unroll
            for (int m = 0; m < 4; m++) {
                int row = wm * 64 + m * 16 + (lane & 15);
                int e   = row * 64 + (kf ^ ((row & 7) << 3));
                a[m] = *reinterpret_cast<const short8*>(&As[e]);
            }
            #pragma unroll
            for (int n = 0; n < 2; n++) {
                int row = wn * 32 + n * 16 + (lane & 15);
                int e   = row * 64 + (kf ^ ((row & 7) << 3));
                b[n] = *reinterpret_cast<const short8*>(&Bs[e]);
            }
            #pragma unroll
            for (int m = 0; m < 4; m++)
                #pragma unroll
                for (int n = 0; n < 2; n++)
                    acc[m][n] = __builtin_amdgcn_mfma_f32_16x16x32_bf16(
                                    a[m], b[n], acc[m][n], 0, 0, 0);
        }
        __syncthreads();
    }

    // ---- epilogue: write fp32 partial tile
    float* dst = partials + (size_t)s * (BATCH * NM1);
    #pragma unroll
    for (int m = 0; m < 4; m++) {
        #pragma unroll
        for (int n = 0; n < 2; n++) {
            int col = n0 + wn * 32 + n * 16 + (lane & 15);
            #pragma unroll
            for (int j = 0; j < 4; j++) {
                int rowi = wm * 64 + m * 16 + ((lane >> 4) * 4 + j);
                dst[(size_t)rowi * NM1 + col] = acc[m][n][j];
            }
        }
    }
}

// ---------------------------------------------------------------- reduce + bias + relu
__global__ void BOW_reduce1(const float* __restrict__ partials,
                            const float* __restrict__ b1,
                            float* __restrict__ h1) {
    int o = blockIdx.x * 256 + threadIdx.x;   // 262144 outputs
    int m = o & (NM1 - 1);
    float s = b1[m];
    #pragma unroll
    for (int sp = 0; sp < SPLITK; sp++) s += partials[(size_t)sp * (BATCH * NM1) + o];
    h1[o] = fmaxf(s, 0.f);
}

// ---------------------------------------------------------------- small fp32 GEMM
// out[256][N] = relu(A[256][K] @ Bw[N][K]^T + bias), tile 32x32, BK=32
__global__ void BOW_gemm_f32(const float* __restrict__ A,
                             const float* __restrict__ Bw,
                             const float* __restrict__ bias,
                             float* __restrict__ out,
                             int N, int K) {
    __shared__ float As[32][33];
    __shared__ float Bs[32][33];
    int tid = threadIdx.x;
    int i0 = blockIdx.y * 32, n0 = blockIdx.x * 32;
    int r = tid >> 5, c = tid & 31;
    int ty = tid >> 4, tx = tid & 15;
    float a2[2][2] = {{0.f, 0.f}, {0.f, 0.f}};

    for (int k0 = 0; k0 < K; k0 += 32) {
        #pragma unroll
        for (int rr = 0; rr < 4; rr++) {
            As[r + rr * 8][c] = A[(size_t)(i0 + r + rr * 8) * K + k0 + c];
            Bs[r + rr * 8][c] = Bw[(size_t)(n0 + r + rr * 8) * K + k0 + c];
        }
        __syncthreads();
        #pragma unroll
        for (int k = 0; k < 32; k++) {
            float av0 = As[ty * 2][k],     av1 = As[ty * 2 + 1][k];
            float bv0 = Bs[tx * 2][k],     bv1 = Bs[tx * 2 + 1][k];
            a2[0][0] += av0 * bv0; a2[0][1] += av0 * bv1;
            a2[1][0] += av1 * bv0; a2[1][1] += av1 * bv1;
        }
        __syncthreads();
    }
    #pragma unroll
    for (int ii = 0; ii < 2; ii++)
        #pragma unroll
        for (int nn = 0; nn < 2; nn++) {
            int i = i0 + ty * 2 + ii, n = n0 + tx * 2 + nn;
            out[(size_t)i * N + n] = fmaxf(a2[ii][nn] + bias[n], 0.f);
        }
}

// ---------------------------------------------------------------- launcher
extern "C" void kernel_launch(void* const* d_in, const int* in_sizes, int n_in,
                              void* d_out, int out_size, void* d_ws, size_t ws_size,
                              hipStream_t stream) {
    const int*   idx = (const int*)d_in[0];
    const float* W1  = (const float*)d_in[1];
    const float* b1  = (const float*)d_in[2];
    const float* W2  = (const float*)d_in[3];
    const float* b2  = (const float*)d_in[4];
    const float* W3  = (const float*)d_in[5];
    const float* b3  = (const float*)d_in[6];
    float* out = (float*)d_out;

    char* ws = (char*)d_ws;
    __hip_bfloat16* bow = (__hip_bfloat16*)ws;
    float* partials = (float*)(ws + BOW_BYTES);
    float* h1       = (float*)(ws + BOW_BYTES + PART_BYTES);
    float* h2       = h1 + BATCH * NM1;

    BOW_hist2<<<BATCH * 2, 256, 0, stream>>>(idx, bow);
    BOW_gemm1<<<SPLITK * NT, 512, 0, stream>>>(bow, W1, partials);
    BOW_reduce1<<<(BATCH * NM1) / 256, 256, 0, stream>>>(partials, b1, h1);
    BOW_gemm_f32<<<dim3(NM2 / 32, BATCH / 32), 256, 0, stream>>>(h1, W2, b2, h2, NM2, NM1);
    BOW_gemm_f32<<<dim3(NEMB / 32, BATCH / 32), 256, 0, stream>>>(h2, W3, b3, out, NEMB, NM2);
}